// Round 10
// baseline (347.561 us; speedup 1.0000x reference)
//
#include <hip/hip_runtime.h>

typedef __attribute__((ext_vector_type(8))) short short8;
typedef __attribute__((ext_vector_type(4))) float floatx4;
typedef __attribute__((ext_vector_type(2))) float floatx2;

#define LOG2E 1.44269504088896340736f

// raw barrier: drains LDS only; global loads stay in flight
#define BAR() asm volatile("s_waitcnt lgkmcnt(0)\n\ts_barrier" ::: "memory")

__device__ __forceinline__ floatx2 F2(float v) { return (floatx2){v, v}; }

__device__ __forceinline__ unsigned short f2bf(float f) {
  unsigned u = __float_as_uint(f);
  u += 0x7FFFu + ((u >> 16) & 1u);
  return (unsigned short)(u >> 16);
}

__device__ __forceinline__ unsigned cvtpk(float lo, float hi) {
  unsigned r;
  asm("v_cvt_pk_bf16_f32 %0, %1, %2" : "=v"(r) : "v"(lo), "v"(hi));
  return r;
}

// 2 blocks/CU (grid=512): (512,2) -> 128-VGPR cap. Two independent barrier
// domains per CU so one block's waves fill the other's dep-chain stalls
// (R9 post-mortem: all pipes <40% busy -> lockstep-latency bound).
// M=16 MFMA panel duplicates the 8 state rows (broadcast reads, free):
// D rows 8-15 == rows 0-7, so q>>1 selects col-tile, q&1 selects batch-pair.
__global__ __launch_bounds__(512, 2) void tlstm_kernel(
    const float* __restrict__ x, const float* __restrict__ tim,
    const float* __restrict__ Wi, const float* __restrict__ bi,
    const float* __restrict__ Wh, const float* __restrict__ bh,
    float* __restrict__ out)
{
  // state: 8 rows [h0,c0,h1,c1,h2,c2,h3,c3] x 256 k, stride 264 (+8 pad), dbuf
  __shared__ __align__(16) unsigned short Sst[2 * 2112];   // 8.25 KB
  // x-tile: 8 rows (2*batch+parity) x 128 k, stride 136, dbuf
  __shared__ __align__(16) unsigned short Sx[2 * 1088];    // 4.25 KB
  __shared__ __align__(16) float WMt[1020];                // [t][4 batches]

  const int tid = threadIdx.x;
  const int wv  = tid >> 6;        // wave 0..7, owns cols [wv*32, wv*32+32)
  const int l   = tid & 63;
  const int q   = l >> 4;          // 0..3
  const int r   = l & 15;
  const int r8  = r & 7;           // duplicated A-row
  const int q1  = q & 1;           // batch-pair select: batches 2q1, 2q1+1
  const int qt  = q >> 1;          // col-tile select
  const int b0  = blockIdx.x * 4;  // 4 batches per block, 512 blocks

  const int col1 = wv * 32 + r;
  const int col2 = col1 + 16;
  const int wcol = wv * 32 + qt * 16 + r;   // column this lane's proc owns

  // ---- weights for both 16-col tiles into registers (B-operand layout) ----
  short8 wh[2][8];
#pragma unroll
  for (int tx = 0; tx < 2; ++tx)
#pragma unroll
    for (int c = 0; c < 8; ++c)
#pragma unroll
      for (int j = 0; j < 8; ++j)
        wh[tx][c][j] = (short)f2bf(Wh[(c * 32 + q * 8 + j) * 256 + wv * 32 + tx * 16 + r]);
  short8 wi[2][4];
#pragma unroll
  for (int tx = 0; tx < 2; ++tx)
#pragma unroll
    for (int c = 0; c < 4; ++c)
#pragma unroll
      for (int j = 0; j < 8; ++j)
        wi[tx][c][j] = (short)f2bf(Wi[(c * 32 + q * 8 + j) * 256 + wv * 32 + tx * 16 + r]);
  const float bh1 = bh[col1], bh2 = bh[col2];
  const float bi1 = bi[col1], bi2 = bi[col2];

  // ---- loop-invariant addresses (ushort units) ----
  const int raS = r8 * 264 + q * 8;     // state A-frag (+32c, +buf)
  const int raX = r8 * 136 + q * 8;     // x A-frag
  const int ih0 = (4 * q1) * 264 + wcol;  // h-row of batch 2q1 @ wcol
  const int xw  = wv * 136 + 2 * l;       // staging: wave wv -> row wv
  const float* xbase = x + (long)(b0 + (wv >> 1)) * 32768 + (wv & 1) * 128 + 2 * l;

  // ---- one-time init ----
  {
    unsigned* S32 = (unsigned*)Sst;
    for (int i = tid; i < 1056; i += 512) S32[i] = 0;   // zero state buf0
  }
  for (int i = tid; i < 1020; i += 512) {
    int t = i >> 2, bl = i & 3;
    float t0 = tim[(b0 + bl) * 256 + t];
    float t1 = tim[(b0 + bl) * 256 + t + 1];
    WMt[i] = 1.f - 1.f / logf(t1 - t0 + 2.7193f);
  }
  {  // stage pair 0 into Sx buf0
    floatx2 v = *(const floatx2*)xbase;
    *(unsigned*)&Sx[xw] = cvtpk(v.x, v.y);
  }
  __syncthreads();

  // lane state packed as (batch 2q1, batch 2q1+1) pairs at col wcol
  floatx2 cS = F2(0.f), hS = F2(0.f), gS = F2(0.f);
  int xro = 0;   // Sx read buffer offset: 0 / 1088

  // packed gate math, batch-pair lanes: 4 exp2 + 2 rcp per call
  auto proc2 = [&](floatx2 zin, floatx2 cpin, floatx2 wmv, int woff) {
    floatx2 z  = __builtin_elementwise_min(__builtin_elementwise_max(zin,  F2(-10.f)), F2(10.f));
    floatx2 cp = __builtin_elementwise_min(__builtin_elementwise_max(cpin, F2(-10.f)), F2(10.f));
    floatx2 mz = z * F2(-LOG2E);
    floatx2 u  = {__builtin_amdgcn_exp2f(mz.x), __builtin_amdgcn_exp2f(mz.y)};
    floatx2 u2 = u * u;
    floatx2 mc = cp * F2(-2.f * LOG2E);
    floatx2 v  = {__builtin_amdgcn_exp2f(mc.x), __builtin_amdgcn_exp2f(mc.y)};
    floatx2 a1 = u + F2(1.f), a2 = u2 + F2(1.f), a3 = v + F2(1.f);
    floatx2 p12 = a1 * a2;
    floatx2 pr  = p12 * a3;
    floatx2 D   = {__builtin_amdgcn_rcpf(pr.x), __builtin_amdgcn_rcpf(pr.y)};
    floatx2 Da3 = D * a3;
    floatx2 g   = Da3 * a2;                 // sigmoid(z)
    floatx2 ir2 = Da3 * a1;                 // 1/(1+u2)
    floatx2 ir3 = D * p12;                  // 1/(1+v)
    floatx2 Cb  = ir2 - u2 * ir2;           // tanh(z)
    floatx2 Cs  = ir3 - v * ir3;            // tanh(cp)
    floatx2 Cst = cS - Cs * wmv;            // c - Cs*(1-wt)
    floatx2 cn  = g * (Cst + Cb);
    floatx2 s   = Cb * Cb;                  // tanh(Cb) Taylor-13
    floatx2 P   = F2(0.003592028f);
    P = P * s + F2(-0.008863236f);
    P = P * s + F2(0.021869488f);
    P = P * s + F2(-0.053968254f);
    P = P * s + F2(0.133333333f);
    P = P * s + F2(-0.333333333f);
    P = P * s + F2(1.0f);
    floatx2 hn = g * (Cb * P);
    unsigned pk0 = cvtpk(hn.x, cn.x);       // lo=h, hi=c  (batch 2q1)
    unsigned pk1 = cvtpk(hn.y, cn.y);       //              (batch 2q1+1)
    Sst[woff + ih0]       = (unsigned short)pk0;
    Sst[woff + ih0 + 264] = (unsigned short)(pk0 >> 16);
    Sst[woff + ih0 + 528] = (unsigned short)pk1;
    Sst[woff + ih0 + 792] = (unsigned short)(pk1 >> 16);
    cS = cn; gS = g; hS = hn;
  };

  floatx4 xs;  // tile-selected x-proj (+bi): [B0 parA, B0 parB, B1 parA, B1 parB]
  auto loadx = [&]() {
    short8 xf[4];
#pragma unroll
    for (int c = 0; c < 4; ++c)
      xf[c] = *(const short8*)&Sx[xro + raX + 32 * c];
    floatx4 x1 = {bi1, bi1, bi1, bi1};
    floatx4 x2 = {bi2, bi2, bi2, bi2};
#pragma unroll
    for (int c = 0; c < 4; ++c) {
      x1 = __builtin_amdgcn_mfma_f32_16x16x32_bf16(xf[c], wi[0][c], x1, 0, 0, 0);
      x2 = __builtin_amdgcn_mfma_f32_16x16x32_bf16(xf[c], wi[1][c], x2, 0, 0, 0);
    }
    xs = qt ? x2 : x1;
  };

  auto dostep = [&](int roff, int woff, int par, int wmoff) {
    short8 sf[8];
#pragma unroll
    for (int c = 0; c < 8; ++c)
      sf[c] = *(const short8*)&Sst[roff + raS + 32 * c];
    floatx4 a1 = {bh1, bh1, bh1, bh1};
    floatx4 a2 = {bh2, bh2, bh2, bh2};
#pragma unroll
    for (int c = 0; c < 8; ++c) {
      a1 = __builtin_amdgcn_mfma_f32_16x16x32_bf16(sf[c], wh[0][c], a1, 0, 0, 0);
      a2 = __builtin_amdgcn_mfma_f32_16x16x32_bf16(sf[c], wh[1][c], a2, 0, 0, 0);
    }
    floatx4 As = qt ? a2 : a1;
    floatx2 wm = *(const floatx2*)&WMt[wmoff + 2 * q1];
    floatx2 z  = {As[0] + xs[par], As[2] + xs[2 + par]};
    floatx2 cp = {As[1],           As[3]};
    proc2(z, cp, wm, woff);
    BAR();
  };

  for (int p = 0; p < 127; ++p) {
    floatx2 nv = *(const floatx2*)(xbase + (p + 1) * 256);  // next pair's x
    loadx();
    // step A (t = 2p): read buf0, write buf1
    dostep(0, 2112, 0, 8 * p);
    // finish staging next pair into the other x buffer
    *(unsigned*)&Sx[(xro ^ 1088) + xw] = cvtpk(nv.x, nv.y);
    // step B (t = 2p+1): read buf1, write buf0
    dostep(2112, 0, 1, 8 * p + 4);
    xro ^= 1088;
  }

  // tail: t = 254 (step A of pair 127; staged at p=126)
  loadx();
  dostep(0, 2112, 0, 8 * 127);

  // ---- epilogue: res = g_last @ Wh + bh; g-tile into buf0 (all 8 rows hit) ----
  Sst[ih0]       = f2bf(gS.x);  Sst[ih0 + 264] = 0;
  Sst[ih0 + 528] = f2bf(gS.y);  Sst[ih0 + 792] = 0;
  BAR();
  short8 gf[8];
#pragma unroll
  for (int c = 0; c < 8; ++c)
    gf[c] = *(const short8*)&Sst[raS + 32 * c];
  floatx4 r1 = {bh1, bh1, bh1, bh1};
  floatx4 r2 = {bh2, bh2, bh2, bh2};
#pragma unroll
  for (int c = 0; c < 8; ++c) {
    r1 = __builtin_amdgcn_mfma_f32_16x16x32_bf16(gf[c], wh[0][c], r1, 0, 0, 0);
    r2 = __builtin_amdgcn_mfma_f32_16x16x32_bf16(gf[c], wh[1][c], r2, 0, 0, 0);
  }
  floatx4 rs = qt ? r2 : r1;

  const long P  = 2048L * 256;
  const long o0 = (long)(b0 + 2 * q1) * 256;
  const long o1 = o0 + 256;
  out[o0 + wcol]         = rs[0];
  out[o1 + wcol]         = rs[2];
  out[P + o0 + wcol]     = hS.x;
  out[P + o1 + wcol]     = hS.y;
  out[2 * P + o0 + wcol] = cS.x;
  out[2 * P + o1 + wcol] = cS.y;
}

extern "C" void kernel_launch(void* const* d_in, const int* in_sizes, int n_in,
                              void* d_out, int out_size, void* d_ws, size_t ws_size,
                              hipStream_t stream) {
  const float* xin = (const float*)d_in[0];
  const float* tim = (const float*)d_in[1];
  const float* Wi  = (const float*)d_in[2];
  const float* bi  = (const float*)d_in[3];
  const float* Wh  = (const float*)d_in[4];
  const float* bh  = (const float*)d_in[5];
  tlstm_kernel<<<dim3(512), dim3(512), 0, stream>>>(xin, tim, Wi, bi, Wh, bh, (float*)d_out);
}

// Round 11
// 270.187 us; speedup vs baseline: 1.2864x; 1.2864x over previous
//
#include <hip/hip_runtime.h>

typedef __attribute__((ext_vector_type(8))) short short8;
typedef __attribute__((ext_vector_type(4))) float floatx4;
typedef __attribute__((ext_vector_type(2))) float floatx2;
typedef __attribute__((ext_vector_type(2))) unsigned uintx2;

#define NLOG2E -1.44269504088896340736f   // -log2(e): weight pre-scale
#define NLN2   -0.69314718055994530942f   // 1/NLOG2E: epilogue unscale
#define CLMP    14.4269504089f            // = 10 * log2(e): clamp in scaled units

// raw barrier: drains LDS only; global loads stay in flight
#define BAR() asm volatile("s_waitcnt lgkmcnt(0)\n\ts_barrier" ::: "memory")

__device__ __forceinline__ floatx2 F2(float v) { return (floatx2){v, v}; }

__device__ __forceinline__ unsigned short f2bf(float f) {
  unsigned u = __float_as_uint(f);
  u += 0x7FFFu + ((u >> 16) & 1u);
  return (unsigned short)(u >> 16);
}

__device__ __forceinline__ unsigned cvtpk(float lo, float hi) {
  unsigned r;
  asm("v_cvt_pk_bf16_f32 %0, %1, %2" : "=v"(r) : "v"(lo), "v"(hi));
  return r;
}

// 8 waves/CU is the hard operating point (R10: acc-VGPRs count against the
// unified file -> reported ~128 VGPR blocks 2-block co-residency). (512,1)
// takes the 256-cap: the 96-VGPR weight set can never spill (R6 lesson).
__global__ __launch_bounds__(512, 1) void tlstm_kernel(
    const float* __restrict__ x, const float* __restrict__ tim,
    const float* __restrict__ Wi, const float* __restrict__ bi,
    const float* __restrict__ Wh, const float* __restrict__ bh,
    float* __restrict__ out)
{
  // state: 16 rows [h0,c0,...,h7,c7] x 256 k, row stride 264 (+8 pad), dbuf
  __shared__ __align__(16) unsigned short Sst[2 * 4224];   // 16.5 KB
  __shared__ __align__(16) unsigned short Sx[2 * 2176];    //  8.5 KB
  __shared__ __align__(16) float WMt[2048];                // [t][8 batches]

  const int tid = threadIdx.x;
  const int wv  = tid >> 6;        // wave 0..7, owns cols [wv*32, wv*32+32)
  const int l   = tid & 63;
  const int q   = l >> 4;
  const int r   = l & 15;
  const int b0  = blockIdx.x * 8;  // 8 batches per block, 256 blocks

  const int col1 = wv * 32 + r;
  const int col2 = col1 + 16;

  // ---- weights pre-scaled by -log2(e) into registers (B-operand layout) ----
  short8 wh[2][8];
#pragma unroll
  for (int tx = 0; tx < 2; ++tx)
#pragma unroll
    for (int c = 0; c < 8; ++c)
#pragma unroll
      for (int j = 0; j < 8; ++j)
        wh[tx][c][j] = (short)f2bf(NLOG2E * Wh[(c * 32 + q * 8 + j) * 256 + wv * 32 + tx * 16 + r]);
  short8 wi[2][4];
#pragma unroll
  for (int tx = 0; tx < 2; ++tx)
#pragma unroll
    for (int c = 0; c < 4; ++c)
#pragma unroll
      for (int j = 0; j < 8; ++j)
        wi[tx][c][j] = (short)f2bf(NLOG2E * Wi[(c * 32 + q * 8 + j) * 256 + wv * 32 + tx * 16 + r]);
  const float bh1 = NLOG2E * bh[col1], bh2 = NLOG2E * bh[col2];
  const float bi1 = NLOG2E * bi[col1], bi2 = NLOG2E * bi[col2];

  // ---- loop-invariant addresses (ushort units) ----
  const int raS  = r * 264 + q * 8;
  const int raX  = r * 136 + q * 8;
  const int ihT1 = (4 * q) * 264 + col1;   // h-row of batch 2q @ col1
  const int xw   = (2 * wv + (l >> 5)) * 136 + 4 * (l & 31);
  const float* xbase = x + (long)(b0 + wv) * 32768 + (l >> 5) * 128 + 4 * (l & 31);

  // ---- one-time init ----
  {
    unsigned* S32 = (unsigned*)Sst;
    for (int i = tid; i < 2112; i += 512) S32[i] = 0;   // zero state buf0
  }
  for (int i = tid; i < 2040; i += 512) {
    int t = i >> 3, bl = i & 7;
    float t0 = tim[(b0 + bl) * 256 + t];
    float t1 = tim[(b0 + bl) * 256 + t + 1];
    WMt[i] = 1.f - 1.f / logf(t1 - t0 + 2.7193f);
  }
  {  // stage pairs 0 AND 1 (loadx(p+1) runs mid-pair, needs pair-ahead staging)
    floatx4 v0 = *(const floatx4*)xbase;
    uintx2 p0 = {cvtpk(v0.x, v0.y), cvtpk(v0.z, v0.w)};
    *(uintx2*)&Sx[xw] = p0;
    floatx4 v1 = *(const floatx4*)(xbase + 256);
    uintx2 p1 = {cvtpk(v1.x, v1.y), cvtpk(v1.z, v1.w)};
    *(uintx2*)&Sx[2176 + xw] = p1;
  }
  __syncthreads();

  // lane state, batch-packed per tile: T1=(col1), T2=(col2); .x=batch 2q, .y=2q+1
  floatx2 cT1 = F2(0.f), cT2 = F2(0.f);
  floatx2 hT1 = F2(0.f), hT2 = F2(0.f);
  floatx2 gT1 = F2(0.f), gT2 = F2(0.f);
  int xro = 0;

  // gate math (z,cp arrive pre-scaled by -log2e): 4 exp2 + 2 rcp per call
  auto proc2 = [&](floatx2 zin, floatx2 cpin, floatx2& cio, floatx2& gio,
                   floatx2& hio, floatx2 wm, int ih, int woff) {
    floatx2 z  = __builtin_elementwise_min(__builtin_elementwise_max(zin,  F2(-CLMP)), F2(CLMP));
    floatx2 cp = __builtin_elementwise_min(__builtin_elementwise_max(cpin, F2(-CLMP)), F2(CLMP));
    floatx2 u  = {__builtin_amdgcn_exp2f(z.x), __builtin_amdgcn_exp2f(z.y)};   // e^{-z}
    floatx2 u2 = u * u;
    floatx2 c2 = cp + cp;
    floatx2 v  = {__builtin_amdgcn_exp2f(c2.x), __builtin_amdgcn_exp2f(c2.y)}; // e^{-2cp}
    floatx2 a1 = u + F2(1.f), a2 = u2 + F2(1.f), a3 = v + F2(1.f);
    floatx2 p12 = a1 * a2;
    floatx2 pr  = p12 * a3;
    floatx2 D   = {__builtin_amdgcn_rcpf(pr.x), __builtin_amdgcn_rcpf(pr.y)};
    floatx2 Da3 = D * a3;
    floatx2 g   = Da3 * a2;                 // sigmoid(z_true)
    floatx2 ir2 = Da3 * a1;                 // 1/(1+u2)
    floatx2 ir3 = D * p12;                  // 1/(1+v)
    floatx2 Cb  = ir2 - u2 * ir2;           // tanh(z_true)
    floatx2 Cs  = ir3 - v * ir3;            // tanh(cp_true)
    floatx2 Cst = cio - Cs * wm;            // c - Cs*(1-wt)
    floatx2 cn  = g * (Cst + Cb);
    floatx2 s   = Cb * Cb;                  // tanh(Cb) Taylor-13
    floatx2 P   = F2(0.003592028f);
    P = P * s + F2(-0.008863236f);
    P = P * s + F2(0.021869488f);
    P = P * s + F2(-0.053968254f);
    P = P * s + F2(0.133333333f);
    P = P * s + F2(-0.333333333f);
    P = P * s + F2(1.0f);
    floatx2 hn = g * (Cb * P);
    unsigned pk0 = cvtpk(hn.x, cn.x);       // batch 2q:   lo=h, hi=c
    unsigned pk1 = cvtpk(hn.y, cn.y);       // batch 2q+1
    Sst[woff + ih]       = (unsigned short)pk0;
    Sst[woff + ih + 264] = (unsigned short)(pk0 >> 16);
    Sst[woff + ih + 528] = (unsigned short)pk1;
    Sst[woff + ih + 792] = (unsigned short)(pk1 >> 16);
    cio = cn; gio = g; hio = hn;
  };

  auto loadx = [&](int xoff, floatx4& x1o, floatx4& x2o) {
    short8 xf[4];
#pragma unroll
    for (int c = 0; c < 4; ++c)
      xf[c] = *(const short8*)&Sx[xoff + raX + 32 * c];
    floatx4 x1 = {bi1, bi1, bi1, bi1};
    floatx4 x2 = {bi2, bi2, bi2, bi2};
#pragma unroll
    for (int c = 0; c < 4; ++c) {
      x1 = __builtin_amdgcn_mfma_f32_16x16x32_bf16(xf[c], wi[0][c], x1, 0, 0, 0);
      x2 = __builtin_amdgcn_mfma_f32_16x16x32_bf16(xf[c], wi[1][c], x2, 0, 0, 0);
    }
    x1o = x1; x2o = x2;
  };

  auto dostep = [&](int roff, int woff, floatx4 xa1, floatx4 xa2, int par, int wmoff) {
    short8 sf[8];
#pragma unroll
    for (int c = 0; c < 8; ++c)
      sf[c] = *(const short8*)&Sst[roff + raS + 32 * c];
    floatx4 a1 = {bh1, bh1, bh1, bh1};
#pragma unroll
    for (int c = 0; c < 8; ++c)
      a1 = __builtin_amdgcn_mfma_f32_16x16x32_bf16(sf[c], wh[0][c], a1, 0, 0, 0);
    floatx4 a2 = {bh2, bh2, bh2, bh2};
#pragma unroll
    for (int c = 0; c < 8; ++c)
      a2 = __builtin_amdgcn_mfma_f32_16x16x32_bf16(sf[c], wh[1][c], a2, 0, 0, 0);
    floatx2 wm = *(const floatx2*)&WMt[wmoff];
    // tile1 proc depends only on a1 -> its trans chain overlaps a2's MFMAs
    proc2((floatx2){a1[0] + xa1[par], a1[2] + xa1[2 + par]},
          (floatx2){a1[1], a1[3]}, cT1, gT1, hT1, wm, ihT1, woff);
    proc2((floatx2){a2[0] + xa2[par], a2[2] + xa2[2 + par]},
          (floatx2){a2[1], a2[3]}, cT2, gT2, hT2, wm, ihT1 + 16, woff);
    BAR();
  };

  floatx4 xc1, xc2;  // current pair's x-proj (+bi), both tiles
  loadx(0, xc1, xc2);

  for (int p = 0; p < 127; ++p) {
    const int pn = (p < 125) ? p + 2 : 127;               // pair to stage
    floatx4 nv = *(const floatx4*)(xbase + (long)pn * 256);
    // step A (t=2p): read buf0, write buf1
    dostep(0, 4224, xc1, xc2, 0, 16 * p + 2 * q);
    // stage pair pn into current (dead) x buffer; visible after B's BAR
    {
      uintx2 pk = {cvtpk(nv.x, nv.y), cvtpk(nv.z, nv.w)};
      *(uintx2*)&Sx[xro + xw] = pk;
    }
    // pair p+1 x-projection: independent of step B -> fills its stalls
    floatx4 xn1, xn2;
    loadx(xro ^ 2176, xn1, xn2);
    // step B (t=2p+1): read buf1, write buf0
    dostep(4224, 0, xc1, xc2, 1, 16 * p + 8 + 2 * q);
    xc1 = xn1; xc2 = xn2;
    xro ^= 2176;
  }

  // tail: t = 254 (step A of pair 127)
  dostep(0, 4224, xc1, xc2, 0, 16 * 127 + 2 * q);

  // ---- epilogue: res = -ln2 * (g_last @ Wh_s + bh_s); g-tile into buf0 ----
  Sst[ihT1]       = f2bf(gT1.x);  Sst[ihT1 + 264] = 0;
  Sst[ihT1 + 528] = f2bf(gT1.y);  Sst[ihT1 + 792] = 0;
  Sst[ihT1 + 16]  = f2bf(gT2.x);  Sst[ihT1 + 280] = 0;
  Sst[ihT1 + 544] = f2bf(gT2.y);  Sst[ihT1 + 808] = 0;
  BAR();
  short8 gf[8];
#pragma unroll
  for (int c = 0; c < 8; ++c)
    gf[c] = *(const short8*)&Sst[raS + 32 * c];
  floatx4 r1 = {bh1, bh1, bh1, bh1};
  floatx4 r2 = {bh2, bh2, bh2, bh2};
#pragma unroll
  for (int c = 0; c < 8; ++c) {
    r1 = __builtin_amdgcn_mfma_f32_16x16x32_bf16(gf[c], wh[0][c], r1, 0, 0, 0);
    r2 = __builtin_amdgcn_mfma_f32_16x16x32_bf16(gf[c], wh[1][c], r2, 0, 0, 0);
  }

  const long P  = 2048L * 256;
  const long o0 = (long)(b0 + 2 * q) * 256;
  const long o1 = o0 + 256;
  out[o0 + col1]         = NLN2 * r1[0];
  out[o1 + col1]         = NLN2 * r1[2];
  out[o0 + col2]         = NLN2 * r2[0];
  out[o1 + col2]         = NLN2 * r2[2];
  out[P + o0 + col1]     = hT1.x;
  out[P + o1 + col1]     = hT1.y;
  out[P + o0 + col2]     = hT2.x;
  out[P + o1 + col2]     = hT2.y;
  out[2 * P + o0 + col1] = cT1.x;
  out[2 * P + o1 + col1] = cT1.y;
  out[2 * P + o0 + col2] = cT2.x;
  out[2 * P + o1 + col2] = cT2.y;
}

extern "C" void kernel_launch(void* const* d_in, const int* in_sizes, int n_in,
                              void* d_out, int out_size, void* d_ws, size_t ws_size,
                              hipStream_t stream) {
  const float* xin = (const float*)d_in[0];
  const float* tim = (const float*)d_in[1];
  const float* Wi  = (const float*)d_in[2];
  const float* bi  = (const float*)d_in[3];
  const float* Wh  = (const float*)d_in[4];
  const float* bh  = (const float*)d_in[5];
  tlstm_kernel<<<dim3(256), dim3(512), 0, stream>>>(xin, tim, Wi, bi, Wh, bh, (float*)d_out);
}

// Round 12
// 248.431 us; speedup vs baseline: 1.3990x; 1.0876x over previous
//
#include <hip/hip_runtime.h>

typedef __attribute__((ext_vector_type(8))) short short8;
typedef __attribute__((ext_vector_type(4))) float floatx4;
typedef __attribute__((ext_vector_type(2))) float floatx2;
typedef __attribute__((ext_vector_type(2))) unsigned uintx2;

#define LOG2E 1.44269504088896340736f

// raw barrier: drains LDS only; global loads stay in flight
#define BAR() asm volatile("s_waitcnt lgkmcnt(0)\n\ts_barrier" ::: "memory")

__device__ __forceinline__ floatx2 F2(float v) { return (floatx2){v, v}; }

__device__ __forceinline__ unsigned short f2bf(float f) {
  unsigned u = __float_as_uint(f);
  u += 0x7FFFu + ((u >> 16) & 1u);
  return (unsigned short)(u >> 16);
}

__device__ __forceinline__ unsigned cvtpk(float lo, float hi) {
  unsigned r;
  asm("v_cvt_pk_bf16_f32 %0, %1, %2" : "=v"(r) : "v"(lo), "v"(hi));
  return r;
}

// 1 block/CU (grid=256): 256-VGPR cap, weights can never spill (R6 lesson).
// LDS state layout (R12): row stride 272 ushorts (544 B) -> read 16B-slot =
// (2r+q+4c) mod 32, exactly 2 lanes/slot (2-way = free, m136). Column twist
// pos(col,row) = col ^ (((row>>2)&3)<<3) spreads write banks 4-way -> 2-way;
// the read base XORs the same rho(r), so the twist cancels and weights stay
// in natural k-order (verified by hand for (row4,col5) and (row13,col37)).
__global__ __launch_bounds__(512, 1) void tlstm_kernel(
    const float* __restrict__ x, const float* __restrict__ tim,
    const float* __restrict__ Wi, const float* __restrict__ bi,
    const float* __restrict__ Wh, const float* __restrict__ bh,
    float* __restrict__ out)
{
  // state: 16 rows [h0,c0,...,h7,c7] x 256 k, row stride 272, double-buffered
  __shared__ __align__(16) unsigned short Sst[2 * 4352];   // 17 KB
  __shared__ __align__(16) unsigned short Sx[2 * 2176];    //  8.5 KB
  __shared__ __align__(16) float WMt[2048];                // [t][8 batches]

  const int tid = threadIdx.x;
  const int wv  = tid >> 6;        // wave 0..7, owns cols [wv*32, wv*32+32)
  const int l   = tid & 63;
  const int q   = l >> 4;
  const int r   = l & 15;
  const int b0  = blockIdx.x * 8;  // 8 batches per block, 256 blocks

  const int col1 = wv * 32 + r;
  const int col2 = col1 + 16;

  // ---- weights for both 16-col tiles into registers (B-operand layout) ----
  short8 wh[2][8];
#pragma unroll
  for (int tx = 0; tx < 2; ++tx)
#pragma unroll
    for (int c = 0; c < 8; ++c)
#pragma unroll
      for (int j = 0; j < 8; ++j)
        wh[tx][c][j] = (short)f2bf(Wh[(c * 32 + q * 8 + j) * 256 + wv * 32 + tx * 16 + r]);
  short8 wi[2][4];
#pragma unroll
  for (int tx = 0; tx < 2; ++tx)
#pragma unroll
    for (int c = 0; c < 4; ++c)
#pragma unroll
      for (int j = 0; j < 8; ++j)
        wi[tx][c][j] = (short)f2bf(Wi[(c * 32 + q * 8 + j) * 256 + wv * 32 + tx * 16 + r]);
  const float bh1 = bh[col1], bh2 = bh[col2];
  const float bi1 = bi[col1], bi2 = bi[col2];

  // ---- loop-invariant addresses (ushort units) ----
  // A-frag read: row r, k-slot q*8 (+32c); XOR rho(r) cancels the write twist
  const int raS = r * 272 + ((q * 8) ^ (((r >> 2) & 3) << 3));
  const int raX = r * 136 + q * 8;
  // write bases: rows 4q.. at col1/col2, twisted by rho(row)=q<<3
  const int iA1 = (4 * q) * 272 + (col1 ^ (q << 3));
  const int iA2 = (4 * q) * 272 + (col2 ^ (q << 3));
  const int xw  = (2 * wv + (l >> 5)) * 136 + 4 * (l & 31);
  const float* xbase = x + (long)(b0 + wv) * 32768 + (l >> 5) * 128 + 4 * (l & 31);

  // ---- one-time init ----
  {
    unsigned* S32 = (unsigned*)Sst;
    for (int i = tid; i < 2176; i += 512) S32[i] = 0;   // zero state buf0
  }
  for (int i = tid; i < 2040; i += 512) {
    int t = i >> 3, bl = i & 7;
    float t0 = tim[(b0 + bl) * 256 + t];
    float t1 = tim[(b0 + bl) * 256 + t + 1];
    WMt[i] = 1.f - 1.f / logf(t1 - t0 + 2.7193f);
  }
  {  // stage pair 0 into Sx buf0
    floatx4 v = *(const floatx4*)xbase;
    uintx2 pk = {cvtpk(v.x, v.y), cvtpk(v.z, v.w)};
    *(uintx2*)&Sx[xw] = pk;
  }
  __syncthreads();

  // lane state as (col1,col2) pairs: P0 = batch 2q, P1 = batch 2q+1
  floatx2 cP0 = F2(0.f), cP1 = F2(0.f);
  floatx2 hP0 = F2(0.f), hP1 = F2(0.f);
  floatx2 gP0 = F2(0.f), gP1 = F2(0.f);
  int xro = 0;

  // packed gate math: 4 exp2 + 2 rcp per call (combined reciprocal)
  auto proc2 = [&](floatx2 zin, floatx2 cpin, floatx2& cio, floatx2& gio,
                   floatx2& hio, float wmv, int ih0, int ih1, int woff) {
    floatx2 z  = __builtin_elementwise_min(__builtin_elementwise_max(zin,  F2(-10.f)), F2(10.f));
    floatx2 cp = __builtin_elementwise_min(__builtin_elementwise_max(cpin, F2(-10.f)), F2(10.f));
    floatx2 mz = z * F2(-LOG2E);
    floatx2 u  = {__builtin_amdgcn_exp2f(mz.x), __builtin_amdgcn_exp2f(mz.y)};
    floatx2 u2 = u * u;
    floatx2 mc = cp * F2(-2.f * LOG2E);
    floatx2 v  = {__builtin_amdgcn_exp2f(mc.x), __builtin_amdgcn_exp2f(mc.y)};
    floatx2 a1 = u + F2(1.f), a2 = u2 + F2(1.f), a3 = v + F2(1.f);
    floatx2 p12 = a1 * a2;
    floatx2 pr  = p12 * a3;
    floatx2 D   = {__builtin_amdgcn_rcpf(pr.x), __builtin_amdgcn_rcpf(pr.y)};
    floatx2 Da3 = D * a3;
    floatx2 g   = Da3 * a2;                 // sigmoid(z)
    floatx2 ir2 = Da3 * a1;                 // 1/(1+u2)
    floatx2 ir3 = D * p12;                  // 1/(1+v)
    floatx2 Cb  = ir2 - u2 * ir2;           // tanh(z)
    floatx2 Cs  = ir3 - v * ir3;            // tanh(cp)
    floatx2 Cst = cio - Cs * F2(wmv);       // c - Cs*(1-wt)
    floatx2 cn  = g * (Cst + Cb);
    floatx2 s   = Cb * Cb;                  // tanh(Cb) Taylor-13
    floatx2 P   = F2(0.003592028f);
    P = P * s + F2(-0.008863236f);
    P = P * s + F2(0.021869488f);
    P = P * s + F2(-0.053968254f);
    P = P * s + F2(0.133333333f);
    P = P * s + F2(-0.333333333f);
    P = P * s + F2(1.0f);
    floatx2 hn = g * (Cb * P);
    unsigned pk0 = cvtpk(hn.x, cn.x);       // col1: lo=h, hi=c
    unsigned pk1 = cvtpk(hn.y, cn.y);       // col2
    Sst[woff + ih0]       = (unsigned short)pk0;
    Sst[woff + ih0 + 272] = (unsigned short)(pk0 >> 16);
    Sst[woff + ih1]       = (unsigned short)pk1;
    Sst[woff + ih1 + 272] = (unsigned short)(pk1 >> 16);
    cio = cn; gio = g; hio = hn;
  };

  floatx4 xa1, xa2;  // x-proj (+bi): [b2q parA, b2q parB, b2q+1 parA, b2q+1 parB]
  auto loadx = [&]() {
    short8 xf[4];
#pragma unroll
    for (int c = 0; c < 4; ++c)
      xf[c] = *(const short8*)&Sx[xro + raX + 32 * c];
    floatx4 x1 = {bi1, bi1, bi1, bi1};
    floatx4 x2 = {bi2, bi2, bi2, bi2};
#pragma unroll
    for (int c = 0; c < 4; ++c) {
      x1 = __builtin_amdgcn_mfma_f32_16x16x32_bf16(xf[c], wi[0][c], x1, 0, 0, 0);
      x2 = __builtin_amdgcn_mfma_f32_16x16x32_bf16(xf[c], wi[1][c], x2, 0, 0, 0);
    }
    xa1 = x1; xa2 = x2;
  };

  auto dostep = [&](int roff, int woff, int par, int wmoff) {
    short8 sf[8];
#pragma unroll
    for (int c = 0; c < 8; ++c)
      sf[c] = *(const short8*)&Sst[roff + raS + 32 * c];
    // 4 independent 4-deep chains: halves exposed MFMA latency
    floatx4 a1e = {bh1, bh1, bh1, bh1}, a1o = {0.f, 0.f, 0.f, 0.f};
    floatx4 a2e = {bh2, bh2, bh2, bh2}, a2o = {0.f, 0.f, 0.f, 0.f};
#pragma unroll
    for (int c = 0; c < 8; c += 2) {
      a1e = __builtin_amdgcn_mfma_f32_16x16x32_bf16(sf[c],     wh[0][c],     a1e, 0, 0, 0);
      a1o = __builtin_amdgcn_mfma_f32_16x16x32_bf16(sf[c + 1], wh[0][c + 1], a1o, 0, 0, 0);
      a2e = __builtin_amdgcn_mfma_f32_16x16x32_bf16(sf[c],     wh[1][c],     a2e, 0, 0, 0);
      a2o = __builtin_amdgcn_mfma_f32_16x16x32_bf16(sf[c + 1], wh[1][c + 1], a2o, 0, 0, 0);
    }
    floatx4 A1 = a1e + a1o;
    floatx4 A2 = a2e + a2o;
    floatx2 wm = *(const floatx2*)&WMt[wmoff];
    floatx2 z0  = {A1[0] + xa1[par],     A2[0] + xa2[par]};
    floatx2 cp0 = {A1[1],                A2[1]};
    floatx2 z1  = {A1[2] + xa1[2 + par], A2[2] + xa2[2 + par]};
    floatx2 cp1 = {A1[3],                A2[3]};
    proc2(z0, cp0, cP0, gP0, hP0, wm.x, iA1,       iA2,       woff);
    proc2(z1, cp1, cP1, gP1, hP1, wm.y, iA1 + 544, iA2 + 544, woff);
    BAR();
  };

  for (int p = 0; p < 127; ++p) {
    floatx4 nv = *(const floatx4*)(xbase + (p + 1) * 256);  // next pair's x
    loadx();
    // step A (t = 2p): read buf0, write buf1
    dostep(0, 4352, 0, 16 * p + 2 * q);
    {  // finish staging next pair into the other x buffer
      uintx2 pk = {cvtpk(nv.x, nv.y), cvtpk(nv.z, nv.w)};
      *(uintx2*)&Sx[(xro ^ 2176) + xw] = pk;
    }
    // step B (t = 2p+1): read buf1, write buf0
    dostep(4352, 0, 1, 16 * p + 8 + 2 * q);
    xro ^= 2176;
  }

  // tail: t = 254 (step A of pair 127; staged at p=126)
  loadx();
  dostep(0, 4352, 0, 16 * 127 + 2 * q);

  // ---- epilogue: res = g_last @ Wh + bh; g-tile into buf0 ----
  Sst[iA1]       = f2bf(gP0.x);  Sst[iA1 + 272] = 0;
  Sst[iA1 + 544] = f2bf(gP1.x);  Sst[iA1 + 816] = 0;
  Sst[iA2]       = f2bf(gP0.y);  Sst[iA2 + 272] = 0;
  Sst[iA2 + 544] = f2bf(gP1.y);  Sst[iA2 + 816] = 0;
  BAR();
  short8 gf[8];
#pragma unroll
  for (int c = 0; c < 8; ++c)
    gf[c] = *(const short8*)&Sst[raS + 32 * c];
  floatx4 r1 = {bh1, bh1, bh1, bh1};
  floatx4 r2 = {bh2, bh2, bh2, bh2};
#pragma unroll
  for (int c = 0; c < 8; ++c) {
    r1 = __builtin_amdgcn_mfma_f32_16x16x32_bf16(gf[c], wh[0][c], r1, 0, 0, 0);
    r2 = __builtin_amdgcn_mfma_f32_16x16x32_bf16(gf[c], wh[1][c], r2, 0, 0, 0);
  }

  const long P  = 2048L * 256;
  const long o0 = (long)(b0 + 2 * q) * 256;
  const long o1 = o0 + 256;
  out[o0 + col1]         = r1[0];
  out[o1 + col1]         = r1[2];
  out[o0 + col2]         = r2[0];
  out[o1 + col2]         = r2[2];
  out[P + o0 + col1]     = hP0.x;
  out[P + o1 + col1]     = hP1.x;
  out[P + o0 + col2]     = hP0.y;
  out[P + o1 + col2]     = hP1.y;
  out[2 * P + o0 + col1] = cP0.x;
  out[2 * P + o1 + col1] = cP1.x;
  out[2 * P + o0 + col2] = cP0.y;
  out[2 * P + o1 + col2] = cP1.y;
}

extern "C" void kernel_launch(void* const* d_in, const int* in_sizes, int n_in,
                              void* d_out, int out_size, void* d_ws, size_t ws_size,
                              hipStream_t stream) {
  const float* xin = (const float*)d_in[0];
  const float* tim = (const float*)d_in[1];
  const float* Wi  = (const float*)d_in[2];
  const float* bi  = (const float*)d_in[3];
  const float* Wh  = (const float*)d_in[4];
  const float* bh  = (const float*)d_in[5];
  tlstm_kernel<<<dim3(256), dim3(512), 0, stream>>>(xin, tim, Wi, bi, Wh, bh, (float*)d_out);
}